// Round 1
// baseline (117.623 us; speedup 1.0000x reference)
//
#include <hip/hip_runtime.h>
#include <hip/hip_bf16.h>

#define BATCH  4096
#define DIM    1024
#define NCHUNK 16          // column chunks (256 cols each)
#define RB     128         // rows per block
#define BK     64          // K tile
#define INVT   14.285714285714286f
#define MSHIFT 14.285714285714286f
#define EPSV   1e-8f
#define NEGINF -3.0e38f

typedef __bf16 bf16x8 __attribute__((ext_vector_type(8)));
typedef float  f32x4  __attribute__((ext_vector_type(4)));
typedef __attribute__((address_space(3))) void lds_void;
typedef __attribute__((address_space(1))) void gl_void;

// Branchless sorted-desc top-5 insert (9 min/max ops).
__device__ __forceinline__ void top5_insert(float (&t)[5], float v) {
  float a = fmaxf(t[4], v), b;
  b = t[3]; t[4] = fminf(b, a); a = fmaxf(b, a);
  b = t[2]; t[3] = fminf(b, a); a = fmaxf(b, a);
  b = t[1]; t[2] = fminf(b, a); a = fmaxf(b, a);
  b = t[0]; t[1] = fminf(b, a); t[0] = fmaxf(b, a);
}

// ---------------- kernel 1: row L2-normalize fp32 -> bf16 ----------------
__global__ __launch_bounds__(256) void k_normalize(const float* __restrict__ X,
                                                   unsigned short* __restrict__ F) {
  const int row = blockIdx.x;
  const int t = threadIdx.x;
  const float4 v = ((const float4*)(X + (size_t)row * DIM))[t];
  float ss = v.x*v.x + v.y*v.y + v.z*v.z + v.w*v.w;
#pragma unroll
  for (int m = 32; m >= 1; m >>= 1) ss += __shfl_xor(ss, m);
  __shared__ float wsum[4];
  if ((t & 63) == 0) wsum[t >> 6] = ss;
  __syncthreads();
  const float tot = wsum[0] + wsum[1] + wsum[2] + wsum[3];
  const float inv = 1.0f / fmaxf(sqrtf(tot), 1e-12f);
  ushort4 o;
  o.x = __builtin_bit_cast(unsigned short, (__bf16)(v.x * inv));
  o.y = __builtin_bit_cast(unsigned short, (__bf16)(v.y * inv));
  o.z = __builtin_bit_cast(unsigned short, (__bf16)(v.z * inv));
  o.w = __builtin_bit_cast(unsigned short, (__bf16)(v.w * inv));
  ((ushort4*)(F + (size_t)row * DIM))[t] = o;
}

// ---------------- kernel 2: fused sim GEMM + per-row stats ----------------
// grid = (NCHUNK, BATCH/RB). Block: 256 thr = 4 waves; wave w owns rows
// [w*32, w*32+32) of the 128-row tile; sweeps its 256-col chunk in two
// 128-col MFMA tiles. Per-row stats accumulated in registers, merged across
// the 16 lanes holding each row, written per (row, chunk) to STATS.
__global__ __launch_bounds__(256) void k_fused(const unsigned short* __restrict__ F,
                                               const long long* __restrict__ LAB,
                                               float* __restrict__ STATS) {
  __shared__ __align__(16) unsigned short lA[RB * BK];  // 16 KB
  __shared__ __align__(16) unsigned short lB[RB * BK];  // 16 KB

  const int ch  = blockIdx.x;
  const int rb  = blockIdx.y;
  const int tid = threadIdx.x;
  const int w   = tid >> 6;
  const int l   = tid & 63;
  const int l15 = l & 15;
  const int l4  = l >> 4;
  const int swz = (l15 & 7) << 4;  // XOR swizzle (row&7)<<4; row%16 == l15 here
  const int co  = l4 * 16;

  const int rowbase = rb * RB;
  const int wrow0   = rowbase + w * 32;

  // This lane's 8 output rows (C layout: row = (lane>>4)*4 + reg, col = lane&15)
  int rl[8], grow[8];
#pragma unroll
  for (int m = 0; m < 2; ++m)
#pragma unroll
    for (int j = 0; j < 4; ++j) {
      const int ri = m * 4 + j;
      const int r  = wrow0 + m * 16 + l4 * 4 + j;
      grow[ri] = r;
      rl[ri]   = (int)LAB[r];
    }

  float pe[8], ne[8], cn[8], t5[8][5];
#pragma unroll
  for (int ri = 0; ri < 8; ++ri) {
    pe[ri] = 0.f; ne[ri] = 0.f; cn[ri] = 0.f;
#pragma unroll
    for (int k = 0; k < 5; ++k) t5[ri][k] = NEGINF;
  }

  const f32x4 zero4 = {0.f, 0.f, 0.f, 0.f};

  for (int ct = 0; ct < 2; ++ct) {
    const int colbase = ch * 256 + ct * 128;
    f32x4 acc[2][8];
#pragma unroll
    for (int m = 0; m < 2; ++m)
#pragma unroll
      for (int n = 0; n < 8; ++n) acc[m][n] = zero4;

    for (int kt = 0; kt < DIM / BK; ++kt) {
      __syncthreads();  // previous tile's ds_reads done before overwrite
      // Stage A(128xBK) and B(128xBK), linear LDS dest + inverse-swizzled
      // global source (16B chunk c is fetched from chunk c^(row&7)).
#pragma unroll
      for (int it = 0; it < 4; ++it) {
        const int s = (it * 4 + w) * 64 + l;     // 16B slot in tile
        const int r = s >> 3;                    // row (8 chunks per row)
        const int c = (l & 7) ^ (r & 7);         // source chunk (involution)
        const unsigned short* gA = F + (size_t)(rowbase + r) * DIM + kt * BK + c * 8;
        const unsigned short* gB = F + (size_t)(colbase + r) * DIM + kt * BK + c * 8;
        __builtin_amdgcn_global_load_lds((gl_void*)gA, (lds_void*)((char*)lA + s * 16), 16, 0, 0);
        __builtin_amdgcn_global_load_lds((gl_void*)gB, (lds_void*)((char*)lB + s * 16), 16, 0, 0);
      }
      __syncthreads();  // compiler drains vmcnt(0) here

#pragma unroll
      for (int kk = 0; kk < 2; ++kk) {
        bf16x8 av[2], bv[8];
        const int cx = (kk * 64 + co) ^ swz;
#pragma unroll
        for (int m = 0; m < 2; ++m) {
          const int r = w * 32 + m * 16 + l15;   // A row for this lane
          av[m] = *(const bf16x8*)((const char*)lA + r * 128 + cx);
        }
#pragma unroll
        for (int n = 0; n < 8; ++n) {
          const int r = n * 16 + l15;            // B "row" = column index
          bv[n] = *(const bf16x8*)((const char*)lB + r * 128 + cx);
        }
#pragma unroll
        for (int m = 0; m < 2; ++m)
#pragma unroll
          for (int n = 0; n < 8; ++n)
            acc[m][n] = __builtin_amdgcn_mfma_f32_16x16x32_bf16(av[m], bv[n], acc[m][n], 0, 0, 0);
      }
    }

    // ---- epilogue for this 128-col tile ----
    int cl[8], gcol[8];
#pragma unroll
    for (int n = 0; n < 8; ++n) {
      const int c = colbase + n * 16 + l15;
      gcol[n] = c;
      cl[n]   = (int)LAB[c];
    }
#pragma unroll
    for (int m = 0; m < 2; ++m)
#pragma unroll
      for (int n = 0; n < 8; ++n)
#pragma unroll
        for (int j = 0; j < 4; ++j) {
          const int ri = m * 4 + j;
          float s = acc[m][n][j];
          s = fminf(fmaxf(s, -10.f), 10.f) * INVT;
          const bool same = (rl[ri] == cl[n]);
          const bool eye  = (grow[ri] == gcol[n]);
          const float e = __expf(s - MSHIFT);
          pe[ri] += (same && !eye) ? e : 0.f;
          ne[ri] += same ? 0.f : e;
          cn[ri] += same ? 0.f : 1.f;
          top5_insert(t5[ri], same ? 0.f : s);  // zeros at non-neg slots, per ref
        }
  }

  // ---- merge the 16 lanes (l&15) holding each row: butterfly ----
#pragma unroll
  for (int ri = 0; ri < 8; ++ri) {
#pragma unroll
    for (int msk = 1; msk < 16; msk <<= 1) {
      pe[ri] += __shfl_xor(pe[ri], msk);
      ne[ri] += __shfl_xor(ne[ri], msk);
      cn[ri] += __shfl_xor(cn[ri], msk);
      const float b0 = __shfl_xor(t5[ri][0], msk);
      const float b1 = __shfl_xor(t5[ri][1], msk);
      const float b2 = __shfl_xor(t5[ri][2], msk);
      const float b3 = __shfl_xor(t5[ri][3], msk);
      const float b4 = __shfl_xor(t5[ri][4], msk);
      top5_insert(t5[ri], b0);
      top5_insert(t5[ri], b1);
      top5_insert(t5[ri], b2);
      top5_insert(t5[ri], b3);
      top5_insert(t5[ri], b4);
    }
  }

  if (l15 == 0) {
#pragma unroll
    for (int ri = 0; ri < 8; ++ri) {
      float* dst = STATS + ((size_t)grow[ri] * NCHUNK + ch) * 8;
      dst[0] = pe[ri]; dst[1] = ne[ri]; dst[2] = cn[ri];
      dst[3] = t5[ri][0]; dst[4] = t5[ri][1]; dst[5] = t5[ri][2];
      dst[6] = t5[ri][3]; dst[7] = t5[ri][4];
    }
  }
}

// ---------------- kernel 3: per-row finalize -> per-block partial ----------------
__global__ __launch_bounds__(256) void k_rowloss(const float* __restrict__ STATS,
                                                 float* __restrict__ PART) {
  const int row = blockIdx.x * 256 + threadIdx.x;
  const float EM = __expf(-MSHIFT);  // exp(0 - M): contribution of each non-neg slot
  const float* sp = STATS + (size_t)row * NCHUNK * 8;
  float pe = 0.f, ne = 0.f, cn = 0.f;
  float t5[5] = {NEGINF, NEGINF, NEGINF, NEGINF, NEGINF};
  for (int c = 0; c < NCHUNK; ++c) {
    const float* p = sp + c * 8;
    pe += p[0]; ne += p[1]; cn += p[2];
#pragma unroll
    for (int k = 0; k < 5; ++k) top5_insert(t5, p[3 + k]);
  }
  const float sneg = ne + ((float)BATCH - cn) * EM;  // exp_neg_sum
  int kf = (int)cn; if (kf > 5) kf = 5;              // actual_k
  float Sh = 0.f, eh[5];
#pragma unroll
  for (int k = 0; k < 5; ++k) {
    const float tv = (k < kf) ? t5[k] : 0.f;         // top_negatives
    eh[k] = __expf(tv - MSHIFT);                     // exp_hard
    Sh += eh[k];
  }
  float lsum = 0.f;
#pragma unroll
  for (int k = 0; k < 5; ++k) {
    const float denom = pe + Sh + sneg - eh[k];
    lsum += __logf(pe / (denom + EPSV) + EPSV);
  }
#pragma unroll
  for (int m = 32; m >= 1; m >>= 1) lsum += __shfl_xor(lsum, m);
  __shared__ float wsum[4];
  if ((threadIdx.x & 63) == 0) wsum[threadIdx.x >> 6] = lsum;
  __syncthreads();
  if (threadIdx.x == 0) PART[blockIdx.x] = wsum[0] + wsum[1] + wsum[2] + wsum[3];
}

// ---------------- kernel 4: final deterministic reduce ----------------
__global__ void k_final(const float* __restrict__ PART, float* __restrict__ OUT) {
  if (threadIdx.x == 0) {
    float s = 0.f;
    for (int i = 0; i < 16; ++i) s += PART[i];
    OUT[0] = -s / (float)(BATCH * 5);
  }
}

extern "C" void kernel_launch(void* const* d_in, const int* in_sizes, int n_in,
                              void* d_out, int out_size, void* d_ws, size_t ws_size,
                              hipStream_t stream) {
  const float* X = (const float*)d_in[0];
  const long long* LAB = (const long long*)d_in[1];
  float* OUT = (float*)d_out;

  unsigned short* F = (unsigned short*)d_ws;                                   // 8 MB bf16 normalized
  float* STATS = (float*)((char*)d_ws + (size_t)8 * 1024 * 1024);              // 2 MB
  float* PART  = (float*)((char*)d_ws + (size_t)10 * 1024 * 1024);             // 64 B

  k_normalize<<<BATCH, 256, 0, stream>>>(X, F);
  dim3 g2(NCHUNK, BATCH / RB);
  k_fused<<<g2, 256, 0, stream>>>(F, LAB, STATS);
  k_rowloss<<<BATCH / 256, 256, 0, stream>>>(STATS, PART);
  k_final<<<1, 64, 0, stream>>>(PART, OUT);
}